// Round 15
// baseline (176.625 us; speedup 1.0000x reference)
//
#include <hip/hip_runtime.h>
#include <math.h>

#define EPS 0.3f
#define CAP 64          // fixed per-node edge capacity (Poisson(16): P(deg>64) ~ 1e-19)
#define SPILLCAP 65536  // safety spill list (never used on this input)
#define NPB 256         // partition blocks (chunks)
#define FROW 256        // fp32 LDS row stride (4w x 16r x 256 x 4B = 64KB exactly)
#define RSTR 128        // random-read record stride: [0,64) fp8 x | [64,72) md

typedef __attribute__((ext_vector_type(8))) short bf16x8;
typedef __attribute__((ext_vector_type(4))) float f32x4;
typedef __attribute__((ext_vector_type(2))) float f32x2;

__device__ __forceinline__ short f2bf(float f) {
    union { float f; unsigned u; } v; v.f = f;
    unsigned r = v.u + 0x7FFFu + ((v.u >> 16) & 1u);  // RNE
    return (short)(r >> 16);
}
__device__ __forceinline__ float bf2f(short s) {
    union { unsigned u; float f; } v;
    v.u = ((unsigned)(unsigned short)s) << 16;
    return v.f;
}
__device__ __forceinline__ int f2bf_pk(float lo, float hi) {
#if __has_builtin(__builtin_amdgcn_cvt_pk_bf16_f32)
    auto r = __builtin_amdgcn_cvt_pk_bf16_f32(lo, hi);
    int out; __builtin_memcpy(&out, &r, 4);
    return out;
#else
    return ((int)(unsigned short)f2bf(lo)) | (((int)(unsigned short)f2bf(hi)) << 16);
#endif
}
// tanh via HW exp: 1 - 2/(1+e^{2x}); saturates correctly, ~1e-6 rel err.
__device__ __forceinline__ float fast_tanh(float x) {
    return 1.0f - 2.0f / (1.0f + __expf(2.0f * x));
}

// ---- fp8 e4m3fn conversion (R30): HW cvt when available, SW fallback ----
#if __has_builtin(__builtin_amdgcn_cvt_pk_f32_fp8) && __has_builtin(__builtin_amdgcn_cvt_pk_fp8_f32)
#define Q2F_LO(w)        __builtin_amdgcn_cvt_pk_f32_fp8((w), false)
#define Q2F_HI(w)        __builtin_amdgcn_cvt_pk_f32_fp8((w), true)
#define F2Q_LO(a,b,old)  __builtin_amdgcn_cvt_pk_fp8_f32((a),(b),(old),false)
#define F2Q_HI(a,b,old)  __builtin_amdgcn_cvt_pk_fp8_f32((a),(b),(old),true)
#else
__device__ __forceinline__ float fp8_dec1(unsigned c) {
    unsigned em = c & 0x7Fu;
    unsigned bits = ((c & 0x80u) << 24) | ((em + 0x3C0u) << 20);
    if (em == 0) bits &= 0x80000000u;
    union { unsigned u; float f; } v; v.u = bits; return v.f;
}
__device__ __forceinline__ unsigned fp8_enc1(float f) {
    union { float f; unsigned u; } v; v.f = f;
    unsigned s = (v.u >> 24) & 0x80u;
    unsigned a = v.u & 0x7FFFFFFFu;
    unsigned t = a + 0x7FFFFu + ((a >> 20) & 1u);   // RNE at 3 mantissa bits
    int em = (int)(t >> 20) - 0x3C0;
    if (em < 1) return s;                            // flush denormal -> 0
    if (em > 0x7E) return s | 0x7Eu;                 // sat to 448
    return s | (unsigned)em;
}
__device__ __forceinline__ f32x2 q2f2_sw(int w, int hi) {
    unsigned bb = hi ? ((unsigned)w >> 16) : (unsigned)w;
    f32x2 r; r.x = fp8_dec1(bb & 0xFFu); r.y = fp8_dec1((bb >> 8) & 0xFFu);
    return r;
}
__device__ __forceinline__ int f2q2_sw(float a, float b, int old, int hi) {
    unsigned p = fp8_enc1(a) | (fp8_enc1(b) << 8);
    return hi ? ((old & 0x0000FFFF) | (int)(p << 16))
              : ((old & (int)0xFFFF0000) | (int)p);
}
#define Q2F_LO(w)        q2f2_sw((w), 0)
#define Q2F_HI(w)        q2f2_sw((w), 1)
#define F2Q_LO(a,b,old)  f2q2_sw((a),(b),(old),0)
#define F2Q_HI(a,b,old)  f2q2_sw((a),(b),(old),1)
#endif

// async 16B/lane global->LDS row copy: per-lane global addr, wave-uniform
// LDS base; lane i lands at base + i*16 (HW semantics). No VGPR round-trip.
__device__ __forceinline__ void async_row16(const float* g, float* l) {
    __builtin_amdgcn_global_load_lds(
        (const __attribute__((address_space(1))) unsigned int*)g,
        (__attribute__((address_space(3))) unsigned int*)l,
        16, 0, 0);
}

// K1 (R29): per-chunk LDS counting-sort into 256 FINE bins (dst>>8);
// wave-shuffle scan (1 barrier). Also converts w fp32->bf16, zeroes spillN.
__global__ __launch_bounds__(256) void part_init(
    const int* __restrict__ src, const int* __restrict__ dst, int E,
    const float* __restrict__ w, short* __restrict__ wb,
    int* __restrict__ spillN,
    unsigned* __restrict__ part2, unsigned short* __restrict__ hoff2, int CS)
{
    extern __shared__ unsigned sbuf[];          // CS entries
    __shared__ int lh[256], lcur[256];
    __shared__ int wsum[4];
    int b = blockIdx.x, tid = threadIdx.x;
    if (b < 64) wb[b * 256 + tid] = f2bf(w[b * 256 + tid]);
    if (b == 0 && tid == 0) *spillN = 0;

    int e0 = b * CS, e1 = min(e0 + CS, E);
    lh[tid] = 0;
    __syncthreads();
    for (int i = e0 + tid; i < e1; i += 256)
        atomicAdd(&lh[dst[i] >> 8], 1);
    __syncthreads();
    int v = lh[tid];

    int x = v;
    #pragma unroll
    for (int off = 1; off < 64; off <<= 1) {
        int y = __shfl_up(x, off, 64);
        if ((tid & 63) >= off) x += y;
    }
    if ((tid & 63) == 63) wsum[tid >> 6] = x;   // wave totals
    __syncthreads();
    int base = 0;
    #pragma unroll
    for (int wv = 0; wv < 4; ++wv)
        base += (wv < (tid >> 6)) ? wsum[wv] : 0;
    int incl = base + x;
    int excl = incl - v;

    lcur[tid] = excl;
    hoff2[b * 257 + tid] = (unsigned short)excl;
    if (tid == 255) hoff2[b * 257 + 256] = (unsigned short)incl;
    __syncthreads();
    for (int i = e0 + tid; i < e1; i += 256) {
        int d = dst[i];
        int slot = atomicAdd(&lcur[d >> 8], 1);
        sbuf[slot] = ((unsigned)(d & 255) << 16) | ((unsigned)src[i] & 0xFFFFu);
    }
    __syncthreads();
    int tot = e1 - e0;
    for (int i = tid; i < tot; i += 256)
        part2[(size_t)b * CS + i] = sbuf[i];
}

// K2 (R31): bin-exclusive bucket fill + t1 MFMA with async fp32 staging.
// R14 post-mortem: fp8 gave ~null -> fetch granule is 128B; an x-row was
// already 1 line and md was a SECOND line. Fix: pack both into ONE 128B
// record rec[t] = [0,64) fp8 x | [64,72) float2 (gb,d) -> 1 random line
// per edge. Disjoint-field writes: bin path d at +68 (both recs), t1 path
// x at +0..64 + gb0 at +64 (rec0); gather_mid x1 + gb1 (rec1).
__global__ __launch_bounds__(256) void bins_t1(
    const unsigned* __restrict__ part2, const unsigned short* __restrict__ hoff2,
    int* __restrict__ cnt, unsigned short* __restrict__ esrc2,
    unsigned* __restrict__ spill, int* __restrict__ spillN,
    const float* __restrict__ h, const short* __restrict__ wb,
    const float* __restrict__ t1b, const float* __restrict__ gw,
    short* __restrict__ XAh, unsigned char* __restrict__ rec0,
    unsigned char* __restrict__ rec1, float* __restrict__ ga0,
    int N, int NBINS, int CS)
{
    __shared__ float lds[4][16 * FROW];       // 64KB exactly
    int tid = threadIdx.x;

    if ((int)blockIdx.x < NBINS) {
        int b = blockIdx.x;
        int t0 = b << 8;
        int* lcur = (int*)&lds[0][0];         // 256 cursors (1KB of the 64KB)
        lcur[tid] = 0;
        __syncthreads();
        int o0 = hoff2[tid * 257 + b];
        int o1 = hoff2[tid * 257 + b + 1];
        const unsigned* seg = part2 + (size_t)tid * CS;
        for (int i = o0; i < o1; ++i) {
            unsigned e = seg[i];              // plain cached load (R24)
            int dl = (int)(e >> 16);
            int slot = atomicAdd(&lcur[dl], 1);
            if (slot < CAP) {
                esrc2[(size_t)(t0 + dl) * CAP + slot] = (unsigned short)(e & 0xFFFFu);
            } else {
                int sp = atomicAdd(spillN, 1);
                if (sp < SPILLCAP)
                    spill[sp] = ((unsigned)(t0 + dl) << 16) | (e & 0xFFFFu);
            }
        }
        __syncthreads();
        int t = t0 + tid;
        if (t < N) {
            int dg = lcur[tid];
            cnt[t] = dg;
            float dval = rsqrtf(fmaxf((float)dg, 1.0f));
            *(float*)(rec0 + (size_t)t * RSTR + 68) = dval;   // md0.y (d)
            *(float*)(rec1 + (size_t)t * RSTR + 68) = dval;   // md1.y (d)
        }
        return;
    }

    // ---- t1 path: x0 = relu(h @ w^T + b); bf16 + fp8-record stores ----
    int bid = blockIdx.x - NBINS;
    int wave = tid >> 6;
    int lane = tid & 63;
    int l15 = lane & 15, quad = lane >> 4;
    int M0 = (bid * 4 + wave) * 16;
    if (M0 >= N) return;                       // wave-uniform; no barriers below
    int rlim = N - M0;                         // rows valid in this tile (<=16)

    float* myl = &lds[wave][0];
    const float* hb = h + (size_t)M0 * 256;
    #pragma unroll
    for (int r = 0; r < 16; ++r) {
        int rr = min(r, rlim - 1);            // clamp tail (outputs masked)
        async_row16(&hb[(size_t)rr * 256 + lane * 4], &myl[r * FROW]);
    }
    asm volatile("s_waitcnt vmcnt(0)" ::: "memory");
    __builtin_amdgcn_sched_barrier(0);        // rule #18: pin the wait

    f32x4 acc[4];
    #pragma unroll
    for (int nt = 0; nt < 4; ++nt) acc[nt] = (f32x4){0.f, 0.f, 0.f, 0.f};

    const short* wq = wb + quad * 8;
    #pragma unroll
    for (int kc = 0; kc < 256; kc += 32) {
        const float* ap = &myl[l15 * FROW + kc + quad * 8];
        float4 a0 = *(const float4*)ap;
        float4 a1 = *(const float4*)(ap + 4);
        union { int i[4]; bf16x8 v; } u;
        u.i[0] = f2bf_pk(a0.x, a0.y);
        u.i[1] = f2bf_pk(a0.z, a0.w);
        u.i[2] = f2bf_pk(a1.x, a1.y);
        u.i[3] = f2bf_pk(a1.z, a1.w);
        bf16x8 af = u.v;
        #pragma unroll
        for (int nt = 0; nt < 4; ++nt) {
            bf16x8 bf = *(const bf16x8*)(wq + (size_t)(nt * 16 + l15) * 256 + kc);
            acc[nt] = __builtin_amdgcn_mfma_f32_16x16x32_bf16(af, bf, acc[nt], 0, 0, 0);
        }
    }

    float pa[4] = {0.f, 0.f, 0.f, 0.f};
    float pb[4] = {0.f, 0.f, 0.f, 0.f};
    #pragma unroll
    for (int nt = 0; nt < 4; ++nt) {
        int n = nt * 16 + l15;
        float bias = t1b[n];
        float gd = gw[n], gs = gw[64 + n];
        #pragma unroll
        for (int r = 0; r < 4; ++r) {
            int row = quad * 4 + r;
            if (row < rlim) {
                float x = fmaxf(acc[nt][r] + bias, 0.f);
                XAh[(size_t)(M0 + row) * 64 + n] = f2bf(x);
                rec0[(size_t)(M0 + row) * RSTR + n] =
                    (unsigned char)(F2Q_LO(x, x, 0) & 0xFF);
                pa[r] += x * gd;
                pb[r] += x * gs;
            }
        }
    }
    #pragma unroll
    for (int off = 1; off < 16; off <<= 1) {
        #pragma unroll
        for (int r = 0; r < 4; ++r) {
            pa[r] += __shfl_xor(pa[r], off, 64);
            pb[r] += __shfl_xor(pb[r], off, 64);
        }
    }
    if (l15 == 0) {
        #pragma unroll
        for (int r = 0; r < 4; ++r) {
            int row = quad * 4 + r;
            if (row < rlim) {
                ga0[M0 + row] = pa[r];
                *(float*)(rec0 + (size_t)(M0 + row) * RSTR + 64) = pb[r]; // gb0
            }
        }
    }
}

// Gather core v8 (R31): ONE 128B record line per edge — md at rec+64,
// fp8 x at rec+0..64. Residual rawh stays exact bf16. Accumulation f32.
__device__ __forceinline__ void gather_core8(
    const int* __restrict__ cnt, const unsigned short* __restrict__ esrc2,
    const float* __restrict__ a, const unsigned char* __restrict__ rec,
    const unsigned* __restrict__ spill, const int* __restrict__ spillN,
    const short* __restrict__ rawh,
    float gbias, int t, int lane, int N, float fin[8])
{
    int g = (lane >> 3) & 3;
    int l = lane & 7;
    int j = lane & 31;
    int hbase = lane & 32;

    int beg = t * CAP;
    int ev_raw = (int)esrc2[beg + j];
    int deg = cnt[t];
    float2 mdt = *(const float2*)(rec + (size_t)t * RSTR + 64);
    float atg = a[t] + gbias;
    int evc = min(ev_raw, N - 1);

    int degrow = min(deg, CAP);
    int lim = min(degrow, 32);
    int lim1 = max(lim - 1, 0);

    int sarr[8];
    #pragma unroll
    for (int k = 0; k < 8; ++k) {
        int m = g + 4 * k;
        sarr[k] = __shfl(evc, hbase + min(m, lim1), 64);
    }
    int2 xr8[8];
    #pragma unroll
    for (int k = 0; k < 8; ++k)
        xr8[k] = *(const int2*)(rec + (size_t)sarr[k] * RSTR + l * 8);

    float2 mde = *(const float2*)(rec + (size_t)evc * RSTR + 64);
    float cv = fast_tanh(atg + mde.x) * mde.y;   // d_t factored out
    float carr[8];
    #pragma unroll
    for (int k = 0; k < 8; ++k) {
        int m = g + 4 * k;
        float c = __shfl(cv, hbase + min(m, lim1), 64);
        carr[k] = (m < lim) ? c : 0.f;
    }

    float acc[8];
    #pragma unroll
    for (int k = 0; k < 8; ++k) acc[k] = 0.f;
    #pragma unroll
    for (int k = 0; k < 8; ++k) {
        float c0 = carr[k];
        f32x2 p0 = Q2F_LO(xr8[k].x), p1 = Q2F_HI(xr8[k].x);
        f32x2 p2 = Q2F_LO(xr8[k].y), p3 = Q2F_HI(xr8[k].y);
        acc[0] += c0 * p0.x; acc[1] += c0 * p0.y;
        acc[2] += c0 * p1.x; acc[3] += c0 * p1.y;
        acc[4] += c0 * p2.x; acc[5] += c0 * p2.y;
        acc[6] += c0 * p3.x; acc[7] += c0 * p3.y;
    }

    // mid tail: slots 32..degrow (Poisson(16): P(deg>32) ~ 1.1e-4)
    for (int i = beg + 32 + g; i < beg + degrow; i += 4) {
        int s0 = (int)esrc2[i];
        float2 m0 = *(const float2*)(rec + (size_t)s0 * RSTR + 64);
        float c0 = fast_tanh(atg + m0.x) * m0.y;
        int2 xv = *(const int2*)(rec + (size_t)s0 * RSTR + l * 8);
        f32x2 p0 = Q2F_LO(xv.x), p1 = Q2F_HI(xv.x);
        f32x2 p2 = Q2F_LO(xv.y), p3 = Q2F_HI(xv.y);
        acc[0] += c0 * p0.x; acc[1] += c0 * p0.y;
        acc[2] += c0 * p1.x; acc[3] += c0 * p1.y;
        acc[4] += c0 * p2.x; acc[5] += c0 * p2.y;
        acc[6] += c0 * p3.x; acc[7] += c0 * p3.y;
    }
    // spill list (deg > CAP; essentially never on this input)
    int sn = min(*spillN, SPILLCAP);
    if (sn > 0) {
        for (int i = 0; i < sn; ++i) {
            unsigned e = spill[i];
            if ((int)(e >> 16) == t && g == 0) {
                int s0 = (int)(e & 0xFFFFu);
                float2 m0 = *(const float2*)(rec + (size_t)s0 * RSTR + 64);
                float c0 = fast_tanh(atg + m0.x) * m0.y;
                int2 xv = *(const int2*)(rec + (size_t)s0 * RSTR + l * 8);
                f32x2 p0 = Q2F_LO(xv.x), p1 = Q2F_HI(xv.x);
                f32x2 p2 = Q2F_LO(xv.y), p3 = Q2F_HI(xv.y);
                acc[0] += c0 * p0.x; acc[1] += c0 * p0.y;
                acc[2] += c0 * p1.x; acc[3] += c0 * p1.y;
                acc[4] += c0 * p2.x; acc[5] += c0 * p2.y;
                acc[6] += c0 * p3.x; acc[7] += c0 * p3.y;
            }
        }
    }

    // reduce across the 4 edge groups (lane bits 3,4; stays within half-wave)
    #pragma unroll
    for (int off = 8; off < 32; off <<= 1) {
        #pragma unroll
        for (int k = 0; k < 8; ++k) acc[k] += __shfl_xor(acc[k], off, 64);
    }

    // epilogue: apply d_t once; residual from EXACT bf16 raw
    bf16x8 rv = *(const bf16x8*)&rawh[(size_t)t * 64 + l * 8];
    #pragma unroll
    for (int k = 0; k < 8; ++k) fin[k] = EPS * bf2f(rv[k]) + mdt.y * acc[k];
}

// layer 0: x1 = EPS*x0 + gather(x0); writes x1 fp8 + gb1 into rec1;
// next-layer gate dot ga1.
__global__ __launch_bounds__(256) void gather_mid(
    const int* __restrict__ cnt, const unsigned short* __restrict__ esrc2,
    const float* __restrict__ a, const unsigned char* __restrict__ rec,
    const unsigned* __restrict__ spill, const int* __restrict__ spillN,
    const short* __restrict__ rawh, const float* __restrict__ gbp,
    unsigned char* __restrict__ recn, const float* __restrict__ gw_next,
    float* __restrict__ ga_next, int N)
{
    int tid = threadIdx.x;
    int t = blockIdx.x * 8 + (tid >> 5);
    int tt = min(t, N - 1);               // clamp: keep all 64 lanes active
    bool valid = (t < N);
    int lane = tid & 63;
    int g = (lane >> 3) & 3, l = lane & 7;
    float fin[8];
    gather_core8(cnt, esrc2, a, rec, spill, spillN, rawh, gbp[0], tt, lane, N, fin);

    if (g == 0 && valid) {
        int lo = F2Q_LO(fin[0], fin[1], 0);
        lo = F2Q_HI(fin[2], fin[3], lo);
        int hi = F2Q_LO(fin[4], fin[5], 0);
        hi = F2Q_HI(fin[6], fin[7], hi);
        int2 o; o.x = lo; o.y = hi;
        *(int2*)(recn + (size_t)tt * RSTR + l * 8) = o;
    }
    float av = 0.f, bv = 0.f;
    #pragma unroll
    for (int k = 0; k < 8; ++k) {
        av += fin[k] * gw_next[l * 8 + k];
        bv += fin[k] * gw_next[64 + l * 8 + k];
    }
    #pragma unroll
    for (int off = 1; off < 8; off <<= 1) {
        av += __shfl_xor(av, off, 64);
        bv += __shfl_xor(bv, off, 64);
    }
    if ((lane & 31) == 0 && valid) {
        ga_next[tt] = av;
        *(float*)(recn + (size_t)tt * RSTR + 64) = bv;   // gb1 (.x of md1)
    }
}

// layer 1: fused gather + t2 matmul + log_softmax; x2 never materialized.
__global__ __launch_bounds__(256) void gather_out(
    const int* __restrict__ cnt, const unsigned short* __restrict__ esrc2,
    const float* __restrict__ a, const unsigned char* __restrict__ rec,
    const unsigned* __restrict__ spill, const int* __restrict__ spillN,
    const short* __restrict__ rawh, const float* __restrict__ gbp,
    const float* __restrict__ t2w, const float* __restrict__ t2b,
    float* __restrict__ out, int N)
{
    int tid = threadIdx.x;
    int t = blockIdx.x * 8 + (tid >> 5);
    int tt = min(t, N - 1);
    bool valid = (t < N);
    int lane = tid & 63;
    int g = (lane >> 3) & 3, l = lane & 7;
    float fin[8];
    gather_core8(cnt, esrc2, a, rec, spill, spillN, rawh, gbp[1], tt, lane, N, fin);

    int j0 = 4 * g;
    float p[4];
    #pragma unroll
    for (int i = 0; i < 4; ++i) {
        const float* w = &t2w[(size_t)(j0 + i) * 64 + l * 8];
        float s = 0.f;
        #pragma unroll
        for (int k = 0; k < 8; ++k) s += fin[k] * w[k];
        p[i] = s;
    }
    #pragma unroll
    for (int off = 1; off < 8; off <<= 1) {
        #pragma unroll
        for (int i = 0; i < 4; ++i) p[i] += __shfl_xor(p[i], off, 64);
    }
    float li[4];
    #pragma unroll
    for (int i = 0; i < 4; ++i) li[i] = p[i] + t2b[j0 + i];
    float m = fmaxf(fmaxf(li[0], li[1]), fmaxf(li[2], li[3]));
    #pragma unroll
    for (int off = 8; off < 32; off <<= 1) m = fmaxf(m, __shfl_xor(m, off, 64));
    float s = 0.f;
    #pragma unroll
    for (int i = 0; i < 4; ++i) s += __expf(li[i] - m);
    #pragma unroll
    for (int off = 8; off < 32; off <<= 1) s += __shfl_xor(s, off, 64);
    float lse = m + __logf(s);
    if (l == 0 && valid) {
        float4 o;
        o.x = li[0] - lse; o.y = li[1] - lse;
        o.z = li[2] - lse; o.w = li[3] - lse;
        *(float4*)&out[(size_t)tt * 16 + j0] = o;
    }
}

extern "C" void kernel_launch(void* const* d_in, const int* in_sizes, int n_in,
                              void* d_out, int out_size, void* d_ws, size_t ws_size,
                              hipStream_t stream) {
    const float* h    = (const float*)d_in[0];
    const int*   src  = (const int*)d_in[1];
    const int*   dst  = (const int*)d_in[2];
    const float* t1w  = (const float*)d_in[3];
    const float* t1b  = (const float*)d_in[4];
    const float* gw   = (const float*)d_in[5];   // [2, 128]
    const float* gbia = (const float*)d_in[6];   // [2]
    const float* t2w  = (const float*)d_in[7];   // [16, 64]
    const float* t2b  = (const float*)d_in[8];   // [16]
    float* out = (float*)d_out;

    int N = in_sizes[0] / 256;                   // 50000 < 65536 (u16 packing)
    int E = in_sizes[1];
    int CS = (E + NPB - 1) / NPB;                // partition chunk (3125)
    int NBINS = (N + 255) / 256;                 // fine bins (196)

    char* p = (char*)d_ws;
    p = (char*)(((size_t)p + 127) & ~(size_t)127);
    unsigned char* rec0 = (unsigned char*)p; p += (size_t)N * RSTR; // x0 fp8 + md0
    unsigned char* rec1 = (unsigned char*)p; p += (size_t)N * RSTR; // x1 fp8 + md1
    short*    XAh    = (short*)p;       p += (size_t)N * 64 * 2;    // x0 bf16 (residual)
    float*    ga0    = (float*)p;       p += (size_t)N * 4;
    float*    ga1    = (float*)p;       p += (size_t)N * 4;
    int*      cnt    = (int*)p;         p += (size_t)N * 4;
    int*      spillN = (int*)p;         p += 16;
    unsigned* spill  = (unsigned*)p;    p += (size_t)SPILLCAP * 4;
    p = (char*)(((size_t)p + 15) & ~(size_t)15);
    unsigned short* esrc2 = (unsigned short*)p; p += (size_t)N * CAP * 2;
    p = (char*)(((size_t)p + 15) & ~(size_t)15);
    unsigned* part2  = (unsigned*)p;    p += (size_t)NPB * CS * 4;
    unsigned short* hoff2 = (unsigned short*)p; p += (size_t)NPB * 257 * 2;
    p = (char*)(((size_t)p + 15) & ~(size_t)15);
    short*    wbf    = (short*)p;

    // K1: fine-bin partition (LDS counting sort, wave-shuffle scan) + w conv
    part_init<<<NPB, 256, (size_t)CS * 4, stream>>>(
        src, dst, E, t1w, wbf, spillN, part2, hoff2, CS);

    // K2: bin-exclusive bucket fill + record md (blocks 0..NBINS-1) || t1 MFMA
    bins_t1<<<NBINS + (N + 63) / 64, 256, 0, stream>>>(
        part2, hoff2, cnt, esrc2, spill, spillN,
        h, wbf, t1b, gw, XAh, rec0, rec1, ga0, N, NBINS, CS);

    int GB = (N + 7) / 8;
    // K3: layer 0 gather — rec1 = EPS*x0 + gather(rec0); layer-1 gate dots
    gather_mid<<<GB, 256, 0, stream>>>(cnt, esrc2, ga0, rec0, spill, spillN,
                                       XAh, gbia, rec1, gw + 128, ga1, N);
    // K4: layer 1 fused gather + t2 + log_softmax
    gather_out<<<GB, 256, 0, stream>>>(cnt, esrc2, ga1, rec1, spill, spillN,
                                       XAh, gbia, t2w, t2b, out, N);
}

// Round 16
// 172.468 us; speedup vs baseline: 1.0241x; 1.0241x over previous
//
#include <hip/hip_runtime.h>
#include <math.h>

#define EPS 0.3f
#define CAP 64          // fixed per-node edge capacity (Poisson(16): P(deg>64) ~ 1e-19)
#define SPILLCAP 65536  // safety spill list (never used on this input)
#define NPB 256         // partition blocks (chunks)
#define FROW 256        // fp32 LDS row stride (4w x 16r x 256 x 4B = 64KB exactly)

typedef __attribute__((ext_vector_type(8))) short bf16x8;
typedef __attribute__((ext_vector_type(4))) float f32x4;
typedef __attribute__((ext_vector_type(2))) float f32x2;

__device__ __forceinline__ short f2bf(float f) {
    union { float f; unsigned u; } v; v.f = f;
    unsigned r = v.u + 0x7FFFu + ((v.u >> 16) & 1u);  // RNE
    return (short)(r >> 16);
}
__device__ __forceinline__ float bf2f(short s) {
    union { unsigned u; float f; } v;
    v.u = ((unsigned)(unsigned short)s) << 16;
    return v.f;
}
__device__ __forceinline__ int f2bf_pk(float lo, float hi) {
#if __has_builtin(__builtin_amdgcn_cvt_pk_bf16_f32)
    auto r = __builtin_amdgcn_cvt_pk_bf16_f32(lo, hi);
    int out; __builtin_memcpy(&out, &r, 4);
    return out;
#else
    return ((int)(unsigned short)f2bf(lo)) | (((int)(unsigned short)f2bf(hi)) << 16);
#endif
}
// tanh via HW exp: 1 - 2/(1+e^{2x}); saturates correctly, ~1e-6 rel err.
__device__ __forceinline__ float fast_tanh(float x) {
    return 1.0f - 2.0f / (1.0f + __expf(2.0f * x));
}

// ---- fp8 e4m3fn conversion (R30): HW cvt when available, SW fallback ----
#if __has_builtin(__builtin_amdgcn_cvt_pk_f32_fp8) && __has_builtin(__builtin_amdgcn_cvt_pk_fp8_f32)
#define Q2F_LO(w)        __builtin_amdgcn_cvt_pk_f32_fp8((w), false)
#define Q2F_HI(w)        __builtin_amdgcn_cvt_pk_f32_fp8((w), true)
#define F2Q_LO(a,b,old)  __builtin_amdgcn_cvt_pk_fp8_f32((a),(b),(old),false)
#define F2Q_HI(a,b,old)  __builtin_amdgcn_cvt_pk_fp8_f32((a),(b),(old),true)
#else
__device__ __forceinline__ float fp8_dec1(unsigned c) {
    unsigned em = c & 0x7Fu;
    unsigned bits = ((c & 0x80u) << 24) | ((em + 0x3C0u) << 20);
    if (em == 0) bits &= 0x80000000u;
    union { unsigned u; float f; } v; v.u = bits; return v.f;
}
__device__ __forceinline__ unsigned fp8_enc1(float f) {
    union { float f; unsigned u; } v; v.f = f;
    unsigned s = (v.u >> 24) & 0x80u;
    unsigned a = v.u & 0x7FFFFFFFu;
    unsigned t = a + 0x7FFFFu + ((a >> 20) & 1u);   // RNE at 3 mantissa bits
    int em = (int)(t >> 20) - 0x3C0;
    if (em < 1) return s;                            // flush denormal -> 0
    if (em > 0x7E) return s | 0x7Eu;                 // sat to 448
    return s | (unsigned)em;
}
__device__ __forceinline__ f32x2 q2f2_sw(int w, int hi) {
    unsigned bb = hi ? ((unsigned)w >> 16) : (unsigned)w;
    f32x2 r; r.x = fp8_dec1(bb & 0xFFu); r.y = fp8_dec1((bb >> 8) & 0xFFu);
    return r;
}
__device__ __forceinline__ int f2q2_sw(float a, float b, int old, int hi) {
    unsigned p = fp8_enc1(a) | (fp8_enc1(b) << 8);
    return hi ? ((old & 0x0000FFFF) | (int)(p << 16))
              : ((old & (int)0xFFFF0000) | (int)p);
}
#define Q2F_LO(w)        q2f2_sw((w), 0)
#define Q2F_HI(w)        q2f2_sw((w), 1)
#define F2Q_LO(a,b,old)  f2q2_sw((a),(b),(old),0)
#define F2Q_HI(a,b,old)  f2q2_sw((a),(b),(old),1)
#endif

// async 16B/lane global->LDS row copy: per-lane global addr, wave-uniform
// LDS base; lane i lands at base + i*16 (HW semantics). No VGPR round-trip.
__device__ __forceinline__ void async_row16(const float* g, float* l) {
    __builtin_amdgcn_global_load_lds(
        (const __attribute__((address_space(1))) unsigned int*)g,
        (__attribute__((address_space(3))) unsigned int*)l,
        16, 0, 0);
}

// K1 (R29): per-chunk LDS counting-sort into 256 FINE bins (dst>>8);
// wave-shuffle scan (1 barrier). Also converts w fp32->bf16, zeroes spillN.
__global__ __launch_bounds__(256) void part_init(
    const int* __restrict__ src, const int* __restrict__ dst, int E,
    const float* __restrict__ w, short* __restrict__ wb,
    int* __restrict__ spillN,
    unsigned* __restrict__ part2, unsigned short* __restrict__ hoff2, int CS)
{
    extern __shared__ unsigned sbuf[];          // CS entries
    __shared__ int lh[256], lcur[256];
    __shared__ int wsum[4];
    int b = blockIdx.x, tid = threadIdx.x;
    if (b < 64) wb[b * 256 + tid] = f2bf(w[b * 256 + tid]);
    if (b == 0 && tid == 0) *spillN = 0;

    int e0 = b * CS, e1 = min(e0 + CS, E);
    lh[tid] = 0;
    __syncthreads();
    for (int i = e0 + tid; i < e1; i += 256)
        atomicAdd(&lh[dst[i] >> 8], 1);
    __syncthreads();
    int v = lh[tid];

    int x = v;
    #pragma unroll
    for (int off = 1; off < 64; off <<= 1) {
        int y = __shfl_up(x, off, 64);
        if ((tid & 63) >= off) x += y;
    }
    if ((tid & 63) == 63) wsum[tid >> 6] = x;   // wave totals
    __syncthreads();
    int base = 0;
    #pragma unroll
    for (int wv = 0; wv < 4; ++wv)
        base += (wv < (tid >> 6)) ? wsum[wv] : 0;
    int incl = base + x;
    int excl = incl - v;

    lcur[tid] = excl;
    hoff2[b * 257 + tid] = (unsigned short)excl;
    if (tid == 255) hoff2[b * 257 + 256] = (unsigned short)incl;
    __syncthreads();
    for (int i = e0 + tid; i < e1; i += 256) {
        int d = dst[i];
        int slot = atomicAdd(&lcur[d >> 8], 1);
        sbuf[slot] = ((unsigned)(d & 255) << 16) | ((unsigned)src[i] & 0xFFFFu);
    }
    __syncthreads();
    int tot = e1 - e0;
    for (int i = tid; i < tot; i += 256)
        part2[(size_t)b * CS + i] = sbuf[i];
}

// K2 (R30): bin-exclusive bucket fill + t1 MFMA with async fp32 staging.
// t1 path also writes the fp8 random-read copy XA8 (x0). XAh bf16 stays
// (exact residual path).
__global__ __launch_bounds__(256) void bins_t1(
    const unsigned* __restrict__ part2, const unsigned short* __restrict__ hoff2,
    int* __restrict__ cnt, unsigned short* __restrict__ esrc2,
    unsigned* __restrict__ spill, int* __restrict__ spillN,
    const float* __restrict__ h, const short* __restrict__ wb,
    const float* __restrict__ t1b, const float* __restrict__ gw,
    short* __restrict__ XAh, unsigned char* __restrict__ XA8,
    float* __restrict__ ga0,
    float* __restrict__ md0f, float* __restrict__ md1f,
    int N, int NBINS, int CS)
{
    __shared__ float lds[4][16 * FROW];       // 64KB exactly
    int tid = threadIdx.x;

    if ((int)blockIdx.x < NBINS) {
        int b = blockIdx.x;
        int t0 = b << 8;
        int* lcur = (int*)&lds[0][0];         // 256 cursors (1KB of the 64KB)
        lcur[tid] = 0;
        __syncthreads();
        int o0 = hoff2[tid * 257 + b];
        int o1 = hoff2[tid * 257 + b + 1];
        const unsigned* seg = part2 + (size_t)tid * CS;
        for (int i = o0; i < o1; ++i) {
            unsigned e = seg[i];              // plain cached load (R24)
            int dl = (int)(e >> 16);
            int slot = atomicAdd(&lcur[dl], 1);
            if (slot < CAP) {
                esrc2[(size_t)(t0 + dl) * CAP + slot] = (unsigned short)(e & 0xFFFFu);
            } else {
                int sp = atomicAdd(spillN, 1);
                if (sp < SPILLCAP)
                    spill[sp] = ((unsigned)(t0 + dl) << 16) | (e & 0xFFFFu);
            }
        }
        __syncthreads();
        int t = t0 + tid;
        if (t < N) {
            int dg = lcur[tid];
            cnt[t] = dg;
            float dval = rsqrtf(fmaxf((float)dg, 1.0f));
            md0f[2 * t + 1] = dval;           // .y of md0 (d)
            md1f[2 * t + 1] = dval;           // .y of md1 (d)
        }
        return;
    }

    // ---- t1 path: x0 = relu(h @ w^T + b); bf16 + fp8 stores ----
    int bid = blockIdx.x - NBINS;
    int wave = tid >> 6;
    int lane = tid & 63;
    int l15 = lane & 15, quad = lane >> 4;
    int M0 = (bid * 4 + wave) * 16;
    if (M0 >= N) return;                       // wave-uniform; no barriers below
    int rlim = N - M0;                         // rows valid in this tile (<=16)

    float* myl = &lds[wave][0];
    const float* hb = h + (size_t)M0 * 256;
    #pragma unroll
    for (int r = 0; r < 16; ++r) {
        int rr = min(r, rlim - 1);            // clamp tail (outputs masked)
        async_row16(&hb[(size_t)rr * 256 + lane * 4], &myl[r * FROW]);
    }
    asm volatile("s_waitcnt vmcnt(0)" ::: "memory");
    __builtin_amdgcn_sched_barrier(0);        // rule #18: pin the wait

    f32x4 acc[4];
    #pragma unroll
    for (int nt = 0; nt < 4; ++nt) acc[nt] = (f32x4){0.f, 0.f, 0.f, 0.f};

    const short* wq = wb + quad * 8;
    #pragma unroll
    for (int kc = 0; kc < 256; kc += 32) {
        const float* ap = &myl[l15 * FROW + kc + quad * 8];
        float4 a0 = *(const float4*)ap;
        float4 a1 = *(const float4*)(ap + 4);
        union { int i[4]; bf16x8 v; } u;
        u.i[0] = f2bf_pk(a0.x, a0.y);
        u.i[1] = f2bf_pk(a0.z, a0.w);
        u.i[2] = f2bf_pk(a1.x, a1.y);
        u.i[3] = f2bf_pk(a1.z, a1.w);
        bf16x8 af = u.v;
        #pragma unroll
        for (int nt = 0; nt < 4; ++nt) {
            bf16x8 bf = *(const bf16x8*)(wq + (size_t)(nt * 16 + l15) * 256 + kc);
            acc[nt] = __builtin_amdgcn_mfma_f32_16x16x32_bf16(af, bf, acc[nt], 0, 0, 0);
        }
    }

    float pa[4] = {0.f, 0.f, 0.f, 0.f};
    float pb[4] = {0.f, 0.f, 0.f, 0.f};
    #pragma unroll
    for (int nt = 0; nt < 4; ++nt) {
        int n = nt * 16 + l15;
        float bias = t1b[n];
        float gd = gw[n], gs = gw[64 + n];
        #pragma unroll
        for (int r = 0; r < 4; ++r) {
            int row = quad * 4 + r;
            if (row < rlim) {
                float x = fmaxf(acc[nt][r] + bias, 0.f);
                XAh[(size_t)(M0 + row) * 64 + n] = f2bf(x);
                XA8[(size_t)(M0 + row) * 64 + n] =
                    (unsigned char)(F2Q_LO(x, x, 0) & 0xFF);
                pa[r] += x * gd;
                pb[r] += x * gs;
            }
        }
    }
    #pragma unroll
    for (int off = 1; off < 16; off <<= 1) {
        #pragma unroll
        for (int r = 0; r < 4; ++r) {
            pa[r] += __shfl_xor(pa[r], off, 64);
            pb[r] += __shfl_xor(pb[r], off, 64);
        }
    }
    if (l15 == 0) {
        #pragma unroll
        for (int r = 0; r < 4; ++r) {
            int row = quad * 4 + r;
            if (row < rlim) {
                ga0[M0 + row] = pa[r];
                md0f[2 * (M0 + row)] = pb[r];  // .x of md0 (gb0)
            }
        }
    }
}

// Gather core v7 (R30): random x reads are fp8 (64B/row); md = one float2
// per edge (L2-resident). Residual rawh stays exact bf16. Accumulation f32.
__device__ __forceinline__ void gather_core7(
    const int* __restrict__ cnt, const unsigned short* __restrict__ esrc2,
    const float* __restrict__ a, const float2* __restrict__ md,
    const unsigned* __restrict__ spill, const int* __restrict__ spillN,
    const unsigned char* __restrict__ x8, const short* __restrict__ rawh,
    float gbias, int t, int lane, int N, float fin[8])
{
    int g = (lane >> 3) & 3;
    int l = lane & 7;
    int j = lane & 31;
    int hbase = lane & 32;

    int beg = t * CAP;
    int ev_raw = (int)esrc2[beg + j];
    int deg = cnt[t];
    float2 mdt = md[t];
    float atg = a[t] + gbias;
    int evc = min(ev_raw, N - 1);

    int degrow = min(deg, CAP);
    int lim = min(degrow, 32);
    int lim1 = max(lim - 1, 0);

    int sarr[8];
    #pragma unroll
    for (int k = 0; k < 8; ++k) {
        int m = g + 4 * k;
        sarr[k] = __shfl(evc, hbase + min(m, lim1), 64);
    }
    int2 xr8[8];
    #pragma unroll
    for (int k = 0; k < 8; ++k)
        xr8[k] = *(const int2*)&x8[(size_t)sarr[k] * 64 + l * 8];

    float2 mde = md[evc];
    float cv = fast_tanh(atg + mde.x) * mde.y;   // d_t factored out
    float carr[8];
    #pragma unroll
    for (int k = 0; k < 8; ++k) {
        int m = g + 4 * k;
        float c = __shfl(cv, hbase + min(m, lim1), 64);
        carr[k] = (m < lim) ? c : 0.f;
    }

    float acc[8];
    #pragma unroll
    for (int k = 0; k < 8; ++k) acc[k] = 0.f;
    #pragma unroll
    for (int k = 0; k < 8; ++k) {
        float c0 = carr[k];
        f32x2 p0 = Q2F_LO(xr8[k].x), p1 = Q2F_HI(xr8[k].x);
        f32x2 p2 = Q2F_LO(xr8[k].y), p3 = Q2F_HI(xr8[k].y);
        acc[0] += c0 * p0.x; acc[1] += c0 * p0.y;
        acc[2] += c0 * p1.x; acc[3] += c0 * p1.y;
        acc[4] += c0 * p2.x; acc[5] += c0 * p2.y;
        acc[6] += c0 * p3.x; acc[7] += c0 * p3.y;
    }

    // mid tail: slots 32..degrow (Poisson(16): P(deg>32) ~ 1.1e-4)
    for (int i = beg + 32 + g; i < beg + degrow; i += 4) {
        int s0 = (int)esrc2[i];
        float2 m0 = md[s0];
        float c0 = fast_tanh(atg + m0.x) * m0.y;
        int2 xv = *(const int2*)&x8[(size_t)s0 * 64 + l * 8];
        f32x2 p0 = Q2F_LO(xv.x), p1 = Q2F_HI(xv.x);
        f32x2 p2 = Q2F_LO(xv.y), p3 = Q2F_HI(xv.y);
        acc[0] += c0 * p0.x; acc[1] += c0 * p0.y;
        acc[2] += c0 * p1.x; acc[3] += c0 * p1.y;
        acc[4] += c0 * p2.x; acc[5] += c0 * p2.y;
        acc[6] += c0 * p3.x; acc[7] += c0 * p3.y;
    }
    // spill list (deg > CAP; essentially never on this input)
    int sn = min(*spillN, SPILLCAP);
    if (sn > 0) {
        for (int i = 0; i < sn; ++i) {
            unsigned e = spill[i];
            if ((int)(e >> 16) == t && g == 0) {
                int s0 = (int)(e & 0xFFFFu);
                float2 m0 = md[s0];
                float c0 = fast_tanh(atg + m0.x) * m0.y;
                int2 xv = *(const int2*)&x8[(size_t)s0 * 64 + l * 8];
                f32x2 p0 = Q2F_LO(xv.x), p1 = Q2F_HI(xv.x);
                f32x2 p2 = Q2F_LO(xv.y), p3 = Q2F_HI(xv.y);
                acc[0] += c0 * p0.x; acc[1] += c0 * p0.y;
                acc[2] += c0 * p1.x; acc[3] += c0 * p1.y;
                acc[4] += c0 * p2.x; acc[5] += c0 * p2.y;
                acc[6] += c0 * p3.x; acc[7] += c0 * p3.y;
            }
        }
    }

    // reduce across the 4 edge groups (lane bits 3,4; stays within half-wave)
    #pragma unroll
    for (int off = 8; off < 32; off <<= 1) {
        #pragma unroll
        for (int k = 0; k < 8; ++k) acc[k] += __shfl_xor(acc[k], off, 64);
    }

    // epilogue: apply d_t once; residual from EXACT bf16 raw
    bf16x8 rv = *(const bf16x8*)&rawh[(size_t)t * 64 + l * 8];
    #pragma unroll
    for (int k = 0; k < 8; ++k) fin[k] = EPS * bf2f(rv[k]) + mdt.y * acc[k];
}

// layer 0: x1 = EPS*x0 + gather(x0); writes x1 as fp8 (only ever read
// randomly); next-layer gate dots (ga1, md1.x)
__global__ __launch_bounds__(256) void gather_mid(
    const int* __restrict__ cnt, const unsigned short* __restrict__ esrc2,
    const float* __restrict__ a, const float2* __restrict__ md,
    const unsigned* __restrict__ spill, const int* __restrict__ spillN,
    const unsigned char* __restrict__ x8, const short* __restrict__ rawh,
    const float* __restrict__ gbp,
    unsigned char* __restrict__ xn8, const float* __restrict__ gw_next,
    float* __restrict__ ga_next, float* __restrict__ md_next_f, int N)
{
    int tid = threadIdx.x;
    int t = blockIdx.x * 8 + (tid >> 5);
    int tt = min(t, N - 1);               // clamp: keep all 64 lanes active
    bool valid = (t < N);
    int lane = tid & 63;
    int g = (lane >> 3) & 3, l = lane & 7;
    float fin[8];
    gather_core7(cnt, esrc2, a, md, spill, spillN, x8, rawh, gbp[0], tt, lane, N, fin);

    if (g == 0 && valid) {
        int lo = F2Q_LO(fin[0], fin[1], 0);
        lo = F2Q_HI(fin[2], fin[3], lo);
        int hi = F2Q_LO(fin[4], fin[5], 0);
        hi = F2Q_HI(fin[6], fin[7], hi);
        int2 o; o.x = lo; o.y = hi;
        *(int2*)&xn8[(size_t)tt * 64 + l * 8] = o;
    }
    float av = 0.f, bv = 0.f;
    #pragma unroll
    for (int k = 0; k < 8; ++k) {
        av += fin[k] * gw_next[l * 8 + k];
        bv += fin[k] * gw_next[64 + l * 8 + k];
    }
    #pragma unroll
    for (int off = 1; off < 8; off <<= 1) {
        av += __shfl_xor(av, off, 64);
        bv += __shfl_xor(bv, off, 64);
    }
    if ((lane & 31) == 0 && valid) {
        ga_next[tt] = av;
        md_next_f[2 * tt] = bv;           // .x of md1 (gb1); .y prefilled
    }
}

// layer 1: fused gather + t2 matmul + log_softmax; x2 never materialized.
__global__ __launch_bounds__(256) void gather_out(
    const int* __restrict__ cnt, const unsigned short* __restrict__ esrc2,
    const float* __restrict__ a, const float2* __restrict__ md,
    const unsigned* __restrict__ spill, const int* __restrict__ spillN,
    const unsigned char* __restrict__ x8, const short* __restrict__ rawh,
    const float* __restrict__ gbp, const float* __restrict__ t2w,
    const float* __restrict__ t2b, float* __restrict__ out, int N)
{
    int tid = threadIdx.x;
    int t = blockIdx.x * 8 + (tid >> 5);
    int tt = min(t, N - 1);
    bool valid = (t < N);
    int lane = tid & 63;
    int g = (lane >> 3) & 3, l = lane & 7;
    float fin[8];
    gather_core7(cnt, esrc2, a, md, spill, spillN, x8, rawh, gbp[1], tt, lane, N, fin);

    int j0 = 4 * g;
    float p[4];
    #pragma unroll
    for (int i = 0; i < 4; ++i) {
        const float* w = &t2w[(size_t)(j0 + i) * 64 + l * 8];
        float s = 0.f;
        #pragma unroll
        for (int k = 0; k < 8; ++k) s += fin[k] * w[k];
        p[i] = s;
    }
    #pragma unroll
    for (int off = 1; off < 8; off <<= 1) {
        #pragma unroll
        for (int i = 0; i < 4; ++i) p[i] += __shfl_xor(p[i], off, 64);
    }
    float li[4];
    #pragma unroll
    for (int i = 0; i < 4; ++i) li[i] = p[i] + t2b[j0 + i];
    float m = fmaxf(fmaxf(li[0], li[1]), fmaxf(li[2], li[3]));
    #pragma unroll
    for (int off = 8; off < 32; off <<= 1) m = fmaxf(m, __shfl_xor(m, off, 64));
    float s = 0.f;
    #pragma unroll
    for (int i = 0; i < 4; ++i) s += __expf(li[i] - m);
    #pragma unroll
    for (int off = 8; off < 32; off <<= 1) s += __shfl_xor(s, off, 64);
    float lse = m + __logf(s);
    if (l == 0 && valid) {
        float4 o;
        o.x = li[0] - lse; o.y = li[1] - lse;
        o.z = li[2] - lse; o.w = li[3] - lse;
        *(float4*)&out[(size_t)tt * 16 + j0] = o;
    }
}

extern "C" void kernel_launch(void* const* d_in, const int* in_sizes, int n_in,
                              void* d_out, int out_size, void* d_ws, size_t ws_size,
                              hipStream_t stream) {
    const float* h    = (const float*)d_in[0];
    const int*   src  = (const int*)d_in[1];
    const int*   dst  = (const int*)d_in[2];
    const float* t1w  = (const float*)d_in[3];
    const float* t1b  = (const float*)d_in[4];
    const float* gw   = (const float*)d_in[5];   // [2, 128]
    const float* gbia = (const float*)d_in[6];   // [2]
    const float* t2w  = (const float*)d_in[7];   // [16, 64]
    const float* t2b  = (const float*)d_in[8];   // [16]
    float* out = (float*)d_out;

    int N = in_sizes[0] / 256;                   // 50000 < 65536 (u16 packing)
    int E = in_sizes[1];
    int CS = (E + NPB - 1) / NPB;                // partition chunk (3125)
    int NBINS = (N + 255) / 256;                 // fine bins (196)

    char* p = (char*)d_ws;
    short*    XAh    = (short*)p;       p += (size_t)N * 64 * 2;   // x0 bf16 (residual)
    unsigned char* XA8 = (unsigned char*)p; p += (size_t)N * 64;   // x0 fp8 (random reads)
    unsigned char* XB8 = (unsigned char*)p; p += (size_t)N * 64;   // x1 fp8 (random reads)
    float*    ga0    = (float*)p;       p += (size_t)N * 4;
    float*    ga1    = (float*)p;       p += (size_t)N * 4;
    float2*   md0    = (float2*)p;      p += (size_t)N * 8;        // (gb0, d)
    float2*   md1    = (float2*)p;      p += (size_t)N * 8;        // (gb1, d)
    int*      cnt    = (int*)p;         p += (size_t)N * 4;
    int*      spillN = (int*)p;         p += 16;
    unsigned* spill  = (unsigned*)p;    p += (size_t)SPILLCAP * 4;
    p = (char*)(((size_t)p + 15) & ~(size_t)15);
    unsigned short* esrc2 = (unsigned short*)p; p += (size_t)N * CAP * 2;
    p = (char*)(((size_t)p + 15) & ~(size_t)15);
    unsigned* part2  = (unsigned*)p;    p += (size_t)NPB * CS * 4;
    unsigned short* hoff2 = (unsigned short*)p; p += (size_t)NPB * 257 * 2;
    p = (char*)(((size_t)p + 15) & ~(size_t)15);
    short*    wbf    = (short*)p;

    // K1: fine-bin partition (LDS counting sort, wave-shuffle scan) + w conv
    part_init<<<NPB, 256, (size_t)CS * 4, stream>>>(
        src, dst, E, t1w, wbf, spillN, part2, hoff2, CS);

    // K2: bin-exclusive bucket fill + md.y (blocks 0..NBINS-1) || t1 MFMA
    bins_t1<<<NBINS + (N + 63) / 64, 256, 0, stream>>>(
        part2, hoff2, cnt, esrc2, spill, spillN,
        h, wbf, t1b, gw, XAh, XA8, ga0, (float*)md0, (float*)md1, N, NBINS, CS);

    int GB = (N + 7) / 8;
    // K3: layer 0 gather — x1(fp8) = EPS*x0 + gather(x0_fp8); layer-1 gate dots
    gather_mid<<<GB, 256, 0, stream>>>(cnt, esrc2, ga0, md0, spill, spillN,
                                       XA8, XAh, gbia, XB8, gw + 128, ga1,
                                       (float*)md1, N);
    // K4: layer 1 fused gather + t2 + log_softmax
    gather_out<<<GB, 256, 0, stream>>>(cnt, esrc2, ga1, md1, spill, spillN,
                                       XB8, XAh, gbia, t2w, t2b, out, N);
}